// Round 1
// baseline (177.304 us; speedup 1.0000x reference)
//
#include <hip/hip_runtime.h>
#include <hip/hip_bf16.h>
#include <stdint.h>

#define T_   2048
#define DM_  1024
#define HD_  64
#define NROW 16384  // B*T

typedef __attribute__((ext_vector_type(8))) __bf16 bf16x8;
typedef __attribute__((ext_vector_type(4))) __bf16 bf16x4;
typedef __attribute__((ext_vector_type(4))) float  f32x4;

// ---------------- kernel 0: pack [Wq|Wk|Wv] -> bf16 B-fragment order ----------
// frag layout: index ((kc*12 + t)*64 + lane)*8 + j  holds W[k = kc*32 + (lane>>4)*8 + j][n = t*16 + (lane&15)]
__global__ void wconv_k(const float* __restrict__ Wq, const float* __restrict__ Wk,
                        const float* __restrict__ Wv, __bf16* __restrict__ wfrag) {
    int tid  = blockIdx.x * 256 + threadIdx.x;   // 24576 total
    int lane = tid & 63;
    int t    = (tid >> 6) % 12;
    int kc   = tid / (12 * 64);
    int c = lane & 15, g = lane >> 4;
    int n = t * 16 + c;
    const float* W = (n < 64) ? Wq : (n < 128) ? Wk : Wv;
    int col = n & 63;
    int k0  = kc * 32 + g * 8;
    __bf16* dst = wfrag + (size_t)tid * 8;
#pragma unroll
    for (int j = 0; j < 8; ++j) dst[j] = (__bf16)W[(k0 + j) * HD_ + col];
}

// ---------------- kernel 1: QKV projection GEMM (16384x192x1024, bf16 MFMA) ---
// grid 256 x 256 threads; wave = one 16-row m-tile, 12 n-tiles (Q|K|V of 64 each)
__global__ __launch_bounds__(256) void proj_k(const float* __restrict__ x,
        const __bf16* __restrict__ wfrag, __bf16* __restrict__ Qb,
        __bf16* __restrict__ Kb, __bf16* __restrict__ Vt) {
    int lane = threadIdx.x & 63, wave = threadIdx.x >> 6;
    int c = lane & 15, g = lane >> 4;
    int row0 = blockIdx.x * 64 + wave * 16;
    const float* xp = x + (size_t)(row0 + c) * DM_ + g * 8;
    f32x4 acc[12];
#pragma unroll
    for (int t = 0; t < 12; ++t) acc[t] = (f32x4)0.f;
    for (int kc = 0; kc < 32; ++kc) {
        const f32x4* ap = (const f32x4*)(xp + kc * 32);
        f32x4 a0 = ap[0], a1 = ap[1];
        bf16x8 af;
#pragma unroll
        for (int j = 0; j < 4; ++j) { af[j] = (__bf16)a0[j]; af[j + 4] = (__bf16)a1[j]; }
        const bf16x8* bp = (const bf16x8*)(wfrag + (size_t)kc * 12 * 512);
#pragma unroll
        for (int t = 0; t < 12; ++t) {
            bf16x8 bf = bp[t * 64 + lane];
            acc[t] = __builtin_amdgcn_mfma_f32_16x16x32_bf16(af, bf, acc[t], 0, 0, 0);
        }
    }
    // C layout: col = lane&15 (n), row = (lane>>4)*4 + r (m)
#pragma unroll
    for (int t = 0; t < 12; ++t) {
        int w    = t >> 2;               // 0=Q 1=K 2=V
        int ncol = (t & 3) * 16 + c;     // 0..63 within the weight
#pragma unroll
        for (int r = 0; r < 4; ++r) {
            int grow = row0 + g * 4 + r;
            float v  = acc[t][r];
            if (w == 0)      Qb[(size_t)grow * HD_ + ncol] = (__bf16)(v * 0.125f); // fold 1/sqrt(64)
            else if (w == 1) Kb[(size_t)grow * HD_ + ncol] = (__bf16)v;
            else             Vt[(size_t)(grow >> 11) * (HD_ * T_) + (size_t)ncol * T_ + (grow & 2047)] = (__bf16)v;
        }
    }
}

// ---------------- kernel 2: causal flash attention --------------------------
// 512 blocks x 128 threads (2 waves x 16 q-rows). S^T = K*Q^T (q lane-local),
// online softmax, P via per-wave LDS relayout, O^T = V^T * P^T, float4 stores.
__global__ __launch_bounds__(128) void attn_k(const __bf16* __restrict__ Qb,
        const __bf16* __restrict__ Kb, const __bf16* __restrict__ Vt,
        const int* __restrict__ vlen, float* __restrict__ out) {
    int bid  = blockIdx.x;
    int half = bid >> 8, idx = bid & 255;
    int b = idx >> 5, p = idx & 31;
    int qb = half ? (63 - p) : p;            // pair big+small causal extents per CU
    int wave = threadIdx.x >> 6, lane = threadIdx.x & 63;
    int c = lane & 15, g = lane >> 4;
    int qg = qb * 32 + wave * 16 + c;        // this lane's q row
    const __bf16* qp = Qb + (size_t)(b * T_ + qg) * HD_ + g * 8;
    bf16x8 qf0 = *(const bf16x8*)qp;
    bf16x8 qf1 = *(const bf16x8*)(qp + 32);
    const __bf16* Kbase = Kb + (size_t)b * T_ * HD_;
    const __bf16* Vbase = Vt + (size_t)b * HD_ * T_;
    f32x4 o0 = (f32x4)0.f, o1 = (f32x4)0.f, o2 = (f32x4)0.f, o3 = (f32x4)0.f;
    float m = -1e30f, lsum = 0.f;
    __shared__ __bf16 plds[2][16][40];       // per-wave P tile, rows padded to 80B
    __bf16 (*pl)[40] = plds[wave];
    int numT = qb + 1;
    for (int kt = 0; kt < numT; ++kt) {
        int kv0 = kt * 32;
        const __bf16* kp = Kbase + (size_t)(kv0 + c) * HD_ + g * 8;
        bf16x8 k00 = *(const bf16x8*)kp;
        bf16x8 k01 = *(const bf16x8*)(kp + 32);
        bf16x8 k10 = *(const bf16x8*)(kp + 16 * HD_);
        bf16x8 k11 = *(const bf16x8*)(kp + 16 * HD_ + 32);
        f32x4 s0 = (f32x4)0.f, s1 = (f32x4)0.f;
        s0 = __builtin_amdgcn_mfma_f32_16x16x32_bf16(k00, qf0, s0, 0, 0, 0);
        s0 = __builtin_amdgcn_mfma_f32_16x16x32_bf16(k01, qf1, s0, 0, 0, 0);
        s1 = __builtin_amdgcn_mfma_f32_16x16x32_bf16(k10, qf0, s1, 0, 0, 0);
        s1 = __builtin_amdgcn_mfma_f32_16x16x32_bf16(k11, qf1, s1, 0, 0, 0);
        float s[8];
#pragma unroll
        for (int r = 0; r < 4; ++r) { s[r] = s0[r]; s[4 + r] = s1[r]; }
        if (kt == numT - 1) {                // only the diagonal tile needs masking
#pragma unroll
            for (int i = 0; i < 8; ++i) {
                int kv = kv0 + (i >> 2) * 16 + g * 4 + (i & 3);
                if (kv > qg) s[i] = -1e30f;
            }
        }
        float tm = s[0];
#pragma unroll
        for (int i = 1; i < 8; ++i) tm = fmaxf(tm, s[i]);
        tm = fmaxf(tm, __shfl_xor(tm, 16));
        tm = fmaxf(tm, __shfl_xor(tm, 32));
        float mn = fmaxf(m, tm);
        float al = __expf(m - mn);
        float ps = 0.f;
#pragma unroll
        for (int i = 0; i < 8; ++i) { s[i] = __expf(s[i] - mn); ps += s[i]; }
        ps += __shfl_xor(ps, 16);
        ps += __shfl_xor(ps, 32);
        lsum = lsum * al + ps;
        m = mn;
        o0 *= al; o1 *= al; o2 *= al; o3 *= al;
        // P (this lane: q=c, kv = mt*16 + g*4 + r) -> LDS as P[q][kv]
        bf16x4 p0, p1;
#pragma unroll
        for (int r = 0; r < 4; ++r) { p0[r] = (__bf16)s[r]; p1[r] = (__bf16)s[4 + r]; }
        *(bf16x4*)&pl[c][g * 4]      = p0;
        *(bf16x4*)&pl[c][16 + g * 4] = p1;
        // B-frag read: P[q=c][kv = g*8 + j], contiguous 16B (wave-private, no barrier)
        bf16x8 pf = *(const bf16x8*)&pl[c][g * 8];
        const __bf16* vp = Vbase + (size_t)c * T_ + kv0 + g * 8;
        bf16x8 v0 = *(const bf16x8*)(vp);
        bf16x8 v1 = *(const bf16x8*)(vp + 16 * T_);
        bf16x8 v2 = *(const bf16x8*)(vp + 32 * T_);
        bf16x8 v3 = *(const bf16x8*)(vp + 48 * T_);
        o0 = __builtin_amdgcn_mfma_f32_16x16x32_bf16(v0, pf, o0, 0, 0, 0);
        o1 = __builtin_amdgcn_mfma_f32_16x16x32_bf16(v1, pf, o1, 0, 0, 0);
        o2 = __builtin_amdgcn_mfma_f32_16x16x32_bf16(v2, pf, o2, 0, 0, 0);
        o3 = __builtin_amdgcn_mfma_f32_16x16x32_bf16(v3, pf, o3, 0, 0, 0);
    }
    float inv  = 1.f / lsum;
    bool  dead = (qg >= vlen[b]);            // causal => k<=q<vl already inside softmax
    float* op  = out + (size_t)(b * T_ + qg) * HD_ + g * 4;
    f32x4 r0 = dead ? (f32x4)0.f : o0 * inv;
    f32x4 r1 = dead ? (f32x4)0.f : o1 * inv;
    f32x4 r2 = dead ? (f32x4)0.f : o2 * inv;
    f32x4 r3 = dead ? (f32x4)0.f : o3 * inv;
    *(f32x4*)(op)      = r0;                 // O^T: row=d (g*4+r within dt*16), col=q
    *(f32x4*)(op + 16) = r1;
    *(f32x4*)(op + 32) = r2;
    *(f32x4*)(op + 48) = r3;
}

extern "C" void kernel_launch(void* const* d_in, const int* in_sizes, int n_in,
                              void* d_out, int out_size, void* d_ws, size_t ws_size,
                              hipStream_t stream) {
    const float* x   = (const float*)d_in[0];
    const float* Wq  = (const float*)d_in[1];
    const float* Wk  = (const float*)d_in[2];
    const float* Wv  = (const float*)d_in[3];
    const int*   vln = (const int*)d_in[4];
    float* out = (float*)d_out;

    __bf16* Qb    = (__bf16*)d_ws;                 // 16384*64 bf16 = 2MB
    __bf16* Kb    = Qb + (size_t)NROW * HD_;       // 2MB
    __bf16* Vt    = Kb + (size_t)NROW * HD_;       // 2MB (V transposed per batch: [b][d][t])
    __bf16* wfrag = Vt + (size_t)NROW * HD_;       // 384KB frag-ordered weights

    wconv_k<<<96, 256, 0, stream>>>(Wq, Wk, Wv, wfrag);
    proj_k <<<256, 256, 0, stream>>>(x, wfrag, Qb, Kb, Vt);
    attn_k <<<512, 128, 0, stream>>>(Qb, Kb, Vt, vln, out);
}

// Round 2
// 175.447 us; speedup vs baseline: 1.0106x; 1.0106x over previous
//
#include <hip/hip_runtime.h>
#include <hip/hip_bf16.h>
#include <stdint.h>

#define T_   2048
#define DM_  1024
#define HD_  64
#define NROW 16384  // B*T

typedef __attribute__((ext_vector_type(8))) __bf16 bf16x8;
typedef __attribute__((ext_vector_type(4))) __bf16 bf16x4;
typedef __attribute__((ext_vector_type(4))) float  f32x4;

// ---------------- kernel 0: pack [Wq|Wk|Wv] -> bf16 B-fragment order ----------
// frag layout: index ((kc*12 + t)*64 + lane)*8 + j  holds W[k = kc*32 + (lane>>4)*8 + j][n = t*16 + (lane&15)]
__global__ void wconv_k(const float* __restrict__ Wq, const float* __restrict__ Wk,
                        const float* __restrict__ Wv, __bf16* __restrict__ wfrag) {
    int tid  = blockIdx.x * 256 + threadIdx.x;   // 24576 total
    int lane = tid & 63;
    int t    = (tid >> 6) % 12;
    int kc   = tid / (12 * 64);
    int c = lane & 15, g = lane >> 4;
    int n = t * 16 + c;
    const float* W = (n < 64) ? Wq : (n < 128) ? Wk : Wv;
    int col = n & 63;
    int k0  = kc * 32 + g * 8;
    __bf16* dst = wfrag + (size_t)tid * 8;
#pragma unroll
    for (int j = 0; j < 8; ++j) dst[j] = (__bf16)W[(k0 + j) * HD_ + col];
}

// ---------------- kernel 1: QKV projection GEMM (16384x192x1024, bf16 MFMA) ---
// 768 blocks x 256 threads; ng = bid>>8 picks Q/K/V (same rows across ng share XCD),
// wave = one 16-row m-tile x 4 n-tiles. 12 waves/CU for latency hiding.
__global__ __launch_bounds__(256) void proj_k(const float* __restrict__ x,
        const __bf16* __restrict__ wfrag, __bf16* __restrict__ Qb,
        __bf16* __restrict__ Kb, __bf16* __restrict__ Vt) {
    int lane = threadIdx.x & 63, wave = threadIdx.x >> 6;
    int ng = blockIdx.x >> 8;        // 0=Q 1=K 2=V
    int rt = blockIdx.x & 255;
    int c = lane & 15, g = lane >> 4;
    int row0 = rt * 64 + wave * 16;
    const float* xp = x + (size_t)(row0 + c) * DM_ + g * 8;
    f32x4 acc[4];
#pragma unroll
    for (int t = 0; t < 4; ++t) acc[t] = (f32x4)0.f;
    for (int kc = 0; kc < 32; ++kc) {
        const f32x4* ap = (const f32x4*)(xp + kc * 32);
        f32x4 a0 = ap[0], a1 = ap[1];
        bf16x8 af;
#pragma unroll
        for (int j = 0; j < 4; ++j) { af[j] = (__bf16)a0[j]; af[j + 4] = (__bf16)a1[j]; }
        const bf16x8* bp = (const bf16x8*)(wfrag + (size_t)kc * 12 * 512) + ng * 256;
#pragma unroll
        for (int t = 0; t < 4; ++t) {
            bf16x8 bf = bp[t * 64 + lane];
            acc[t] = __builtin_amdgcn_mfma_f32_16x16x32_bf16(af, bf, acc[t], 0, 0, 0);
        }
    }
    // C layout: col = lane&15 (n), row = (lane>>4)*4 + r (m)
#pragma unroll
    for (int t = 0; t < 4; ++t) {
        int ncol = t * 16 + c;           // 0..63 within this weight
#pragma unroll
        for (int r = 0; r < 4; ++r) {
            int grow = row0 + g * 4 + r;
            float v  = acc[t][r];
            if (ng == 0)      Qb[(size_t)grow * HD_ + ncol] = (__bf16)(v * 0.125f); // fold 1/sqrt(64)
            else if (ng == 1) Kb[(size_t)grow * HD_ + ncol] = (__bf16)v;
            else              Vt[(size_t)(grow >> 11) * (HD_ * T_) + (size_t)ncol * T_ + (grow & 2047)] = (__bf16)v;
        }
    }
}

// ---------------- kernel 2: causal flash attention --------------------------
// 512 blocks x 128 threads (2 waves x 16 q-rows). S^T = K*Q^T (q lane-local),
// 64 kv per iteration (2 MFMA tiles) for load ILP + halved softmax passes.
__global__ __launch_bounds__(128) void attn_k(const __bf16* __restrict__ Qb,
        const __bf16* __restrict__ Kb, const __bf16* __restrict__ Vt,
        const int* __restrict__ vlen, float* __restrict__ out) {
    int bid  = blockIdx.x;
    int half = bid >> 8, idx = bid & 255;
    int b = idx >> 5, p = idx & 31;
    int qb = half ? (63 - p) : p;            // pair big+small causal extents per CU
    int wave = threadIdx.x >> 6, lane = threadIdx.x & 63;
    int c = lane & 15, g = lane >> 4;
    int qg = qb * 32 + wave * 16 + c;        // this lane's q row
    const __bf16* qp = Qb + (size_t)(b * T_ + qg) * HD_ + g * 8;
    bf16x8 qf0 = *(const bf16x8*)qp;
    bf16x8 qf1 = *(const bf16x8*)(qp + 32);
    const __bf16* Kbase = Kb + (size_t)b * T_ * HD_;
    const __bf16* Vbase = Vt + (size_t)b * HD_ * T_;
    f32x4 o0 = (f32x4)0.f, o1 = (f32x4)0.f, o2 = (f32x4)0.f, o3 = (f32x4)0.f;
    float m = -1e30f, lsum = 0.f;
    __shared__ __bf16 plds[2][16][72];       // per-wave P tile (64 kv), rows padded
    __bf16 (*pl)[72] = plds[wave];
    int nd2 = (qb + 2) >> 1;                 // double-tiles of 64 kv
    for (int kt = 0; kt < nd2; ++kt) {
        int kv0 = kt * 64;
        const __bf16* kp = Kbase + (size_t)(kv0 + c) * HD_ + g * 8;
        bf16x8 ka00 = *(const bf16x8*)(kp);
        bf16x8 ka01 = *(const bf16x8*)(kp + 32);
        bf16x8 ka10 = *(const bf16x8*)(kp + 16 * HD_);
        bf16x8 ka11 = *(const bf16x8*)(kp + 16 * HD_ + 32);
        bf16x8 kb00 = *(const bf16x8*)(kp + 32 * HD_);
        bf16x8 kb01 = *(const bf16x8*)(kp + 32 * HD_ + 32);
        bf16x8 kb10 = *(const bf16x8*)(kp + 48 * HD_);
        bf16x8 kb11 = *(const bf16x8*)(kp + 48 * HD_ + 32);
        f32x4 sa0 = (f32x4)0.f, sa1 = (f32x4)0.f, sb0 = (f32x4)0.f, sb1 = (f32x4)0.f;
        sa0 = __builtin_amdgcn_mfma_f32_16x16x32_bf16(ka00, qf0, sa0, 0, 0, 0);
        sa0 = __builtin_amdgcn_mfma_f32_16x16x32_bf16(ka01, qf1, sa0, 0, 0, 0);
        sa1 = __builtin_amdgcn_mfma_f32_16x16x32_bf16(ka10, qf0, sa1, 0, 0, 0);
        sa1 = __builtin_amdgcn_mfma_f32_16x16x32_bf16(ka11, qf1, sa1, 0, 0, 0);
        sb0 = __builtin_amdgcn_mfma_f32_16x16x32_bf16(kb00, qf0, sb0, 0, 0, 0);
        sb0 = __builtin_amdgcn_mfma_f32_16x16x32_bf16(kb01, qf1, sb0, 0, 0, 0);
        sb1 = __builtin_amdgcn_mfma_f32_16x16x32_bf16(kb10, qf0, sb1, 0, 0, 0);
        sb1 = __builtin_amdgcn_mfma_f32_16x16x32_bf16(kb11, qf1, sb1, 0, 0, 0);
        float s[16];
#pragma unroll
        for (int r = 0; r < 4; ++r) {
            s[r] = sa0[r]; s[4 + r] = sa1[r]; s[8 + r] = sb0[r]; s[12 + r] = sb1[r];
        }
        if (kt == nd2 - 1) {                 // only the final double-tile needs masking
#pragma unroll
            for (int i = 0; i < 16; ++i) {
                int kv = kv0 + (i >> 2) * 16 + g * 4 + (i & 3);
                if (kv > qg) s[i] = -1e30f;
            }
        }
        float tm = s[0];
#pragma unroll
        for (int i = 1; i < 16; ++i) tm = fmaxf(tm, s[i]);
        tm = fmaxf(tm, __shfl_xor(tm, 16));
        tm = fmaxf(tm, __shfl_xor(tm, 32));
        float mn = fmaxf(m, tm);
        float al = __expf(m - mn);
        float ps = 0.f;
#pragma unroll
        for (int i = 0; i < 16; ++i) { s[i] = __expf(s[i] - mn); ps += s[i]; }
        ps += __shfl_xor(ps, 16);
        ps += __shfl_xor(ps, 32);
        lsum = lsum * al + ps;
        m = mn;
        o0 *= al; o1 *= al; o2 *= al; o3 *= al;
        // P (this lane: q=c, kv = (i>>2)*16 + g*4 + (i&3)) -> LDS as P[q][kv]
#pragma unroll
        for (int mt = 0; mt < 4; ++mt) {
            bf16x4 pv;
#pragma unroll
            for (int r = 0; r < 4; ++r) pv[r] = (__bf16)s[mt * 4 + r];
            *(bf16x4*)&pl[c][mt * 16 + g * 4] = pv;
        }
        // B-frag reads: P[q=c][kv = tile*32 + g*8 + j], wave-private (no barrier)
        bf16x8 pf0 = *(const bf16x8*)&pl[c][g * 8];
        bf16x8 pf1 = *(const bf16x8*)&pl[c][32 + g * 8];
        const __bf16* vp = Vbase + (size_t)c * T_ + kv0 + g * 8;
        bf16x8 v0a = *(const bf16x8*)(vp);
        bf16x8 v1a = *(const bf16x8*)(vp + 16 * T_);
        bf16x8 v2a = *(const bf16x8*)(vp + 32 * T_);
        bf16x8 v3a = *(const bf16x8*)(vp + 48 * T_);
        bf16x8 v0b = *(const bf16x8*)(vp + 32);
        bf16x8 v1b = *(const bf16x8*)(vp + 16 * T_ + 32);
        bf16x8 v2b = *(const bf16x8*)(vp + 32 * T_ + 32);
        bf16x8 v3b = *(const bf16x8*)(vp + 48 * T_ + 32);
        o0 = __builtin_amdgcn_mfma_f32_16x16x32_bf16(v0a, pf0, o0, 0, 0, 0);
        o1 = __builtin_amdgcn_mfma_f32_16x16x32_bf16(v1a, pf0, o1, 0, 0, 0);
        o2 = __builtin_amdgcn_mfma_f32_16x16x32_bf16(v2a, pf0, o2, 0, 0, 0);
        o3 = __builtin_amdgcn_mfma_f32_16x16x32_bf16(v3a, pf0, o3, 0, 0, 0);
        o0 = __builtin_amdgcn_mfma_f32_16x16x32_bf16(v0b, pf1, o0, 0, 0, 0);
        o1 = __builtin_amdgcn_mfma_f32_16x16x32_bf16(v1b, pf1, o1, 0, 0, 0);
        o2 = __builtin_amdgcn_mfma_f32_16x16x32_bf16(v2b, pf1, o2, 0, 0, 0);
        o3 = __builtin_amdgcn_mfma_f32_16x16x32_bf16(v3b, pf1, o3, 0, 0, 0);
    }
    float inv  = 1.f / lsum;
    bool  dead = (qg >= vlen[b]);            // causal => k<=q<vl already inside softmax
    float* op  = out + (size_t)(b * T_ + qg) * HD_ + g * 4;
    f32x4 r0 = dead ? (f32x4)0.f : o0 * inv;
    f32x4 r1 = dead ? (f32x4)0.f : o1 * inv;
    f32x4 r2 = dead ? (f32x4)0.f : o2 * inv;
    f32x4 r3 = dead ? (f32x4)0.f : o3 * inv;
    *(f32x4*)(op)      = r0;                 // O^T: row=d (g*4+r within dt*16), col=q
    *(f32x4*)(op + 16) = r1;
    *(f32x4*)(op + 32) = r2;
    *(f32x4*)(op + 48) = r3;
}

extern "C" void kernel_launch(void* const* d_in, const int* in_sizes, int n_in,
                              void* d_out, int out_size, void* d_ws, size_t ws_size,
                              hipStream_t stream) {
    const float* x   = (const float*)d_in[0];
    const float* Wq  = (const float*)d_in[1];
    const float* Wk  = (const float*)d_in[2];
    const float* Wv  = (const float*)d_in[3];
    const int*   vln = (const int*)d_in[4];
    float* out = (float*)d_out;

    __bf16* Qb    = (__bf16*)d_ws;                 // 16384*64 bf16 = 2MB
    __bf16* Kb    = Qb + (size_t)NROW * HD_;       // 2MB
    __bf16* Vt    = Kb + (size_t)NROW * HD_;       // 2MB (V transposed per batch: [b][d][t])
    __bf16* wfrag = Vt + (size_t)NROW * HD_;       // 384KB frag-ordered weights

    wconv_k<<<96, 256, 0, stream>>>(Wq, Wk, Wv, wfrag);
    proj_k <<<768, 256, 0, stream>>>(x, wfrag, Qb, Kb, Vt);
    attn_k <<<512, 128, 0, stream>>>(Qb, Kb, Vt, vln, out);
}

// Round 3
// 170.500 us; speedup vs baseline: 1.0399x; 1.0290x over previous
//
#include <hip/hip_runtime.h>
#include <hip/hip_bf16.h>
#include <stdint.h>

#define T_   2048
#define DM_  1024
#define HD_  64
#define NROW 16384  // B*T
#define SPLIT 4     // kv-splits per q-tile (occupancy lever for attn)

typedef __attribute__((ext_vector_type(8))) __bf16 bf16x8;
typedef __attribute__((ext_vector_type(4))) __bf16 bf16x4;
typedef __attribute__((ext_vector_type(4))) float  f32x4;

// ---------------- kernel 0: pack [Wq|Wk|Wv] -> bf16 B-fragment order ----------
// frag layout: index ((kc*12 + t)*64 + lane)*8 + j  holds W[k = kc*32 + (lane>>4)*8 + j][n = t*16 + (lane&15)]
__global__ void wconv_k(const float* __restrict__ Wq, const float* __restrict__ Wk,
                        const float* __restrict__ Wv, __bf16* __restrict__ wfrag) {
    int tid  = blockIdx.x * 256 + threadIdx.x;   // 24576 total
    int lane = tid & 63;
    int t    = (tid >> 6) % 12;
    int kc   = tid / (12 * 64);
    int c = lane & 15, g = lane >> 4;
    int n = t * 16 + c;
    const float* W = (n < 64) ? Wq : (n < 128) ? Wk : Wv;
    int col = n & 63;
    int k0  = kc * 32 + g * 8;
    __bf16* dst = wfrag + (size_t)tid * 8;
#pragma unroll
    for (int j = 0; j < 8; ++j) dst[j] = (__bf16)W[(k0 + j) * HD_ + col];
}

// ---------------- kernel 1: QKV projection GEMM (16384x192x1024, bf16 MFMA) ---
// 768 blocks x 256 threads; ng = bid>>8 picks Q/K/V (same rows across ng share XCD),
// wave = one 16-row m-tile x 4 n-tiles. 12 waves/CU for latency hiding.
__global__ __launch_bounds__(256) void proj_k(const float* __restrict__ x,
        const __bf16* __restrict__ wfrag, __bf16* __restrict__ Qb,
        __bf16* __restrict__ Kb, __bf16* __restrict__ Vt) {
    int lane = threadIdx.x & 63, wave = threadIdx.x >> 6;
    int ng = blockIdx.x >> 8;        // 0=Q 1=K 2=V
    int rt = blockIdx.x & 255;
    int c = lane & 15, g = lane >> 4;
    int row0 = rt * 64 + wave * 16;
    const float* xp = x + (size_t)(row0 + c) * DM_ + g * 8;
    f32x4 acc[4];
#pragma unroll
    for (int t = 0; t < 4; ++t) acc[t] = (f32x4)0.f;
    for (int kc = 0; kc < 32; ++kc) {
        const f32x4* ap = (const f32x4*)(xp + kc * 32);
        f32x4 a0 = ap[0], a1 = ap[1];
        bf16x8 af;
#pragma unroll
        for (int j = 0; j < 4; ++j) { af[j] = (__bf16)a0[j]; af[j + 4] = (__bf16)a1[j]; }
        const bf16x8* bp = (const bf16x8*)(wfrag + (size_t)kc * 12 * 512) + ng * 256;
#pragma unroll
        for (int t = 0; t < 4; ++t) {
            bf16x8 bf = bp[t * 64 + lane];
            acc[t] = __builtin_amdgcn_mfma_f32_16x16x32_bf16(af, bf, acc[t], 0, 0, 0);
        }
    }
    // C layout: col = lane&15 (n), row = (lane>>4)*4 + r (m)
#pragma unroll
    for (int t = 0; t < 4; ++t) {
        int ncol = t * 16 + c;           // 0..63 within this weight
#pragma unroll
        for (int r = 0; r < 4; ++r) {
            int grow = row0 + g * 4 + r;
            float v  = acc[t][r];
            // fold 1/sqrt(64) * log2(e) into Q so softmax runs in exp2 domain
            if (ng == 0)      Qb[(size_t)grow * HD_ + ncol] = (__bf16)(v * 0.18033688f);
            else if (ng == 1) Kb[(size_t)grow * HD_ + ncol] = (__bf16)v;
            else              Vt[(size_t)(grow >> 11) * (HD_ * T_) + (size_t)ncol * T_ + (grow & 2047)] = (__bf16)v;
        }
    }
}

// ---------------- kernel 2: causal flash attention, kv-split partials --------
// 2048 blocks x 128 threads (2 waves x 16 q-rows; 4 kv-splits per q-tile).
// S^T = K*Q^T (q lane-local), online softmax in exp2 domain, P via per-wave LDS
// relayout, O^T = V^T * P^T. Each split writes partial O + (m, l); comb_k merges.
__global__ __launch_bounds__(128) void attn_k(const __bf16* __restrict__ Qb,
        const __bf16* __restrict__ Kb, const __bf16* __restrict__ Vt,
        float* __restrict__ Opart, float* __restrict__ ml) {
    int split = blockIdx.x >> 9;
    int bid2  = blockIdx.x & 511;
    int half = bid2 >> 8, idx = bid2 & 255;
    int b = idx >> 5, p = idx & 31;
    int qb = half ? (63 - p) : p;            // pair big+small causal extents per CU
    int wave = threadIdx.x >> 6, lane = threadIdx.x & 63;
    int c = lane & 15, g = lane >> 4;
    int qg   = qb * 32 + wave * 16 + c;      // this lane's q row
    int tile = b * 128 + qb * 2 + wave;      // 16-row q-tile id (0..1023)
    int nd2  = (qb + 2) >> 1;                // double-tiles of 64 kv
    float m = -1e30f, lsum = 0.f;
    if (split < nd2) {
        const __bf16* qp = Qb + (size_t)(b * T_ + qg) * HD_ + g * 8;
        bf16x8 qf0 = *(const bf16x8*)qp;
        bf16x8 qf1 = *(const bf16x8*)(qp + 32);
        const __bf16* Kbase = Kb + (size_t)b * T_ * HD_;
        const __bf16* Vbase = Vt + (size_t)b * HD_ * T_;
        f32x4 o0 = (f32x4)0.f, o1 = (f32x4)0.f, o2 = (f32x4)0.f, o3 = (f32x4)0.f;
        __shared__ __bf16 plds[2][16][72];   // per-wave P tile (64 kv), rows padded
        __bf16 (*pl)[72] = plds[wave];
        for (int kt = split; kt < nd2; kt += SPLIT) {
            int kv0 = kt * 64;
            const __bf16* kp = Kbase + (size_t)(kv0 + c) * HD_ + g * 8;
            bf16x8 ka00 = *(const bf16x8*)(kp);
            bf16x8 ka01 = *(const bf16x8*)(kp + 32);
            bf16x8 ka10 = *(const bf16x8*)(kp + 16 * HD_);
            bf16x8 ka11 = *(const bf16x8*)(kp + 16 * HD_ + 32);
            bf16x8 kb00 = *(const bf16x8*)(kp + 32 * HD_);
            bf16x8 kb01 = *(const bf16x8*)(kp + 32 * HD_ + 32);
            bf16x8 kb10 = *(const bf16x8*)(kp + 48 * HD_);
            bf16x8 kb11 = *(const bf16x8*)(kp + 48 * HD_ + 32);
            f32x4 sa0 = (f32x4)0.f, sa1 = (f32x4)0.f, sb0 = (f32x4)0.f, sb1 = (f32x4)0.f;
            sa0 = __builtin_amdgcn_mfma_f32_16x16x32_bf16(ka00, qf0, sa0, 0, 0, 0);
            sa0 = __builtin_amdgcn_mfma_f32_16x16x32_bf16(ka01, qf1, sa0, 0, 0, 0);
            sa1 = __builtin_amdgcn_mfma_f32_16x16x32_bf16(ka10, qf0, sa1, 0, 0, 0);
            sa1 = __builtin_amdgcn_mfma_f32_16x16x32_bf16(ka11, qf1, sa1, 0, 0, 0);
            sb0 = __builtin_amdgcn_mfma_f32_16x16x32_bf16(kb00, qf0, sb0, 0, 0, 0);
            sb0 = __builtin_amdgcn_mfma_f32_16x16x32_bf16(kb01, qf1, sb0, 0, 0, 0);
            sb1 = __builtin_amdgcn_mfma_f32_16x16x32_bf16(kb10, qf0, sb1, 0, 0, 0);
            sb1 = __builtin_amdgcn_mfma_f32_16x16x32_bf16(kb11, qf1, sb1, 0, 0, 0);
            float s[16];
#pragma unroll
            for (int r = 0; r < 4; ++r) {
                s[r] = sa0[r]; s[4 + r] = sa1[r]; s[8 + r] = sb0[r]; s[12 + r] = sb1[r];
            }
            if (kt == nd2 - 1) {             // only the final double-tile needs masking
#pragma unroll
                for (int i = 0; i < 16; ++i) {
                    int kv = kv0 + (i >> 2) * 16 + g * 4 + (i & 3);
                    if (kv > qg) s[i] = -1e30f;
                }
            }
            float tm = s[0];
#pragma unroll
            for (int i = 1; i < 16; ++i) tm = fmaxf(tm, s[i]);
            tm = fmaxf(tm, __shfl_xor(tm, 16));
            tm = fmaxf(tm, __shfl_xor(tm, 32));
            float mn = fmaxf(m, tm);
            float al = __builtin_amdgcn_exp2f(m - mn);
            float ps = 0.f;
#pragma unroll
            for (int i = 0; i < 16; ++i) { s[i] = __builtin_amdgcn_exp2f(s[i] - mn); ps += s[i]; }
            ps += __shfl_xor(ps, 16);
            ps += __shfl_xor(ps, 32);
            lsum = lsum * al + ps;
            m = mn;
            o0 *= al; o1 *= al; o2 *= al; o3 *= al;
            // P (this lane: q=c, kv = (i>>2)*16 + g*4 + (i&3)) -> LDS as P[q][kv]
#pragma unroll
            for (int mt = 0; mt < 4; ++mt) {
                bf16x4 pv;
#pragma unroll
                for (int r = 0; r < 4; ++r) pv[r] = (__bf16)s[mt * 4 + r];
                *(bf16x4*)&pl[c][mt * 16 + g * 4] = pv;
            }
            // B-frag reads: P[q=c][kv = tile*32 + g*8 + j], wave-private (no barrier)
            bf16x8 pf0 = *(const bf16x8*)&pl[c][g * 8];
            bf16x8 pf1 = *(const bf16x8*)&pl[c][32 + g * 8];
            const __bf16* vp = Vbase + (size_t)c * T_ + kv0 + g * 8;
            bf16x8 v0a = *(const bf16x8*)(vp);
            bf16x8 v1a = *(const bf16x8*)(vp + 16 * T_);
            bf16x8 v2a = *(const bf16x8*)(vp + 32 * T_);
            bf16x8 v3a = *(const bf16x8*)(vp + 48 * T_);
            bf16x8 v0b = *(const bf16x8*)(vp + 32);
            bf16x8 v1b = *(const bf16x8*)(vp + 16 * T_ + 32);
            bf16x8 v2b = *(const bf16x8*)(vp + 32 * T_ + 32);
            bf16x8 v3b = *(const bf16x8*)(vp + 48 * T_ + 32);
            o0 = __builtin_amdgcn_mfma_f32_16x16x32_bf16(v0a, pf0, o0, 0, 0, 0);
            o1 = __builtin_amdgcn_mfma_f32_16x16x32_bf16(v1a, pf0, o1, 0, 0, 0);
            o2 = __builtin_amdgcn_mfma_f32_16x16x32_bf16(v2a, pf0, o2, 0, 0, 0);
            o3 = __builtin_amdgcn_mfma_f32_16x16x32_bf16(v3a, pf0, o3, 0, 0, 0);
            o0 = __builtin_amdgcn_mfma_f32_16x16x32_bf16(v0b, pf1, o0, 0, 0, 0);
            o1 = __builtin_amdgcn_mfma_f32_16x16x32_bf16(v1b, pf1, o1, 0, 0, 0);
            o2 = __builtin_amdgcn_mfma_f32_16x16x32_bf16(v2b, pf1, o2, 0, 0, 0);
            o3 = __builtin_amdgcn_mfma_f32_16x16x32_bf16(v3b, pf1, o3, 0, 0, 0);
        }
        // partial O^T store: Opart[part][q_local=c][d = dt*16 + g*4 + r]
        float* op = Opart + ((size_t)tile * SPLIT + split) * 1024 + c * 64 + g * 4;
        *(f32x4*)(op)      = o0;
        *(f32x4*)(op + 16) = o1;
        *(f32x4*)(op + 32) = o2;
        *(f32x4*)(op + 48) = o3;
    }
    if (g == 0) {                            // (m, l) per q row; l==0 marks empty split
        float* mlp = ml + ((size_t)tile * SPLIT + split) * 32 + c * 2;
        mlp[0] = m; mlp[1] = lsum;
    }
}

// ---------------- kernel 3: merge kv-split partials, normalize, mask ---------
// 1024 blocks x 256 threads; block = one 16-row q-tile; thread = (q, 4 d's).
__global__ __launch_bounds__(256) void comb_k(const float* __restrict__ Opart,
        const float* __restrict__ ml, const int* __restrict__ vlen,
        float* __restrict__ out) {
    int tile = blockIdx.x;
    int b  = tile >> 7;
    int q0 = (tile & 127) * 16;
    int q  = threadIdx.x >> 4;
    int d0 = (threadIdx.x & 15) * 4;
    int qg = q0 + q;
    const float* mlp = ml + (size_t)tile * SPLIT * 32 + q * 2;
    float mj[SPLIT], lj[SPLIT];
#pragma unroll
    for (int j = 0; j < SPLIT; ++j) { mj[j] = mlp[j * 32]; lj[j] = mlp[j * 32 + 1]; }
    float M = fmaxf(fmaxf(mj[0], mj[1]), fmaxf(mj[2], mj[3]));
    f32x4 acc = (f32x4)0.f;
    float L = 0.f;
#pragma unroll
    for (int j = 0; j < SPLIT; ++j) {
        if (lj[j] > 0.f) {                   // skip empty splits (Opart unwritten there)
            float sc = __builtin_amdgcn_exp2f(mj[j] - M);
            L += lj[j] * sc;
            f32x4 ov = *(const f32x4*)(Opart + ((size_t)tile * SPLIT + j) * 1024 + q * 64 + d0);
            acc += ov * sc;
        }
    }
    float inv = (qg < vlen[b]) ? 1.f / L : 0.f;  // dead rows -> 0
    f32x4 r = acc * inv;
    *(f32x4*)(out + ((size_t)(b * T_) + qg) * HD_ + d0) = r;
}

extern "C" void kernel_launch(void* const* d_in, const int* in_sizes, int n_in,
                              void* d_out, int out_size, void* d_ws, size_t ws_size,
                              hipStream_t stream) {
    const float* x   = (const float*)d_in[0];
    const float* Wq  = (const float*)d_in[1];
    const float* Wk  = (const float*)d_in[2];
    const float* Wv  = (const float*)d_in[3];
    const int*   vln = (const int*)d_in[4];
    float* out = (float*)d_out;

    __bf16* Qb    = (__bf16*)d_ws;                 // 16384*64 bf16 = 2MB
    __bf16* Kb    = Qb + (size_t)NROW * HD_;       // 2MB
    __bf16* Vt    = Kb + (size_t)NROW * HD_;       // 2MB (V transposed per batch: [b][d][t])
    __bf16* wfrag = Vt + (size_t)NROW * HD_;       // 384KB frag-ordered weights
    float*  Opart = (float*)(wfrag + 24576 * 8);   // 1024 tiles x 4 splits x 16x64 f32 = 16MB
    float*  mlbuf = Opart + (size_t)1024 * SPLIT * 1024;  // 512KB (m,l) pairs

    wconv_k<<<96, 256, 0, stream>>>(Wq, Wk, Wv, wfrag);
    proj_k <<<768, 256, 0, stream>>>(x, wfrag, Qb, Kb, Vt);
    attn_k <<<512 * SPLIT, 128, 0, stream>>>(Qb, Kb, Vt, Opart, mlbuf);
    comb_k <<<1024, 256, 0, stream>>>(Opart, mlbuf, vln, out);
}

// Round 4
// 155.510 us; speedup vs baseline: 1.1401x; 1.0964x over previous
//
#include <hip/hip_runtime.h>
#include <hip/hip_bf16.h>
#include <stdint.h>

#define T_   2048
#define DM_  1024
#define HD_  64
#define NROW 16384  // B*T
#define SPLIT 4     // kv-splits per q-tile (occupancy lever for attn)
#define BM   32     // proj rows per block
#define BK   64     // proj k per step

typedef __attribute__((ext_vector_type(8))) __bf16 bf16x8;
typedef __attribute__((ext_vector_type(4))) __bf16 bf16x4;
typedef __attribute__((ext_vector_type(4))) float  f32x4;

// ---------------- kernel 0: pack [Wq|Wk|Wv] -> bf16 B-fragment order ----------
// frag layout: index ((kc*12 + t)*64 + lane)*8 + j  holds W[k = kc*32 + (lane>>4)*8 + j][n = t*16 + (lane&15)]
__global__ void wconv_k(const float* __restrict__ Wq, const float* __restrict__ Wk,
                        const float* __restrict__ Wv, __bf16* __restrict__ wfrag) {
    int tid  = blockIdx.x * 256 + threadIdx.x;   // 24576 total
    int lane = tid & 63;
    int t    = (tid >> 6) % 12;
    int kc   = tid / (12 * 64);
    int c = lane & 15, g = lane >> 4;
    int n = t * 16 + c;
    const float* W = (n < 64) ? Wq : (n < 128) ? Wk : Wv;
    int col = n & 63;
    int k0  = kc * 32 + g * 8;
    __bf16* dst = wfrag + (size_t)tid * 8;
#pragma unroll
    for (int j = 0; j < 8; ++j) dst[j] = (__bf16)W[(k0 + j) * HD_ + col];
}

// ---------------- kernel 1: QKV projection GEMM (16384x192x1024, bf16 MFMA) ---
// LDS-staged double-buffered: coalesced x->LDS (padded), wfrag->LDS via
// global_load_lds (per-block, not per-wave). 512 blocks x 256 thr, 2 blocks/CU.
__global__ __launch_bounds__(256, 2) void proj_k(const float* __restrict__ x,
        const __bf16* __restrict__ wfrag, __bf16* __restrict__ Qb,
        __bf16* __restrict__ Kb, __bf16* __restrict__ Vt) {
    __shared__ __bf16 abuf[2][BM][72];        // A tile bf16, row-padded (+8) -> 2-way only
    __shared__ __bf16 bbuf[2][2][12][512];    // [buf][khalf][t][lane*8] linear frag order
    int tid  = threadIdx.x;
    int lane = tid & 63, wave = tid >> 6;
    int mh = wave >> 1, th = wave & 1;        // wave = 16-row half x 6-t half
    int c = lane & 15, g = lane >> 4;
    int row0 = blockIdx.x * BM;
    int ar = tid >> 3, a0 = (tid & 7) * 8;    // staging: thread = (row, 8-col chunk)
    const float* xrow = x + (size_t)(row0 + ar) * DM_ + a0;

    f32x4 acc[6];
#pragma unroll
    for (int t = 0; t < 6; ++t) acc[t] = (f32x4)0.f;

    // prologue: stage step 0 into buf 0
    {
#pragma unroll
        for (int i = 0; i < 6; ++i) {
            int p = wave * 6 + i;             // 24 (khalf,t) frags split across 4 waves
            int kh = p / 12, tt = p % 12;
            const __bf16* src = wfrag + ((size_t)kh * 12 + tt) * 512 + lane * 8;
            __builtin_amdgcn_global_load_lds(
                (const __attribute__((address_space(1))) void*)src,
                (__attribute__((address_space(3))) void*)&bbuf[0][kh][tt][0], 16, 0, 0);
        }
        f32x4 x0 = *(const f32x4*)(xrow);
        f32x4 x1 = *(const f32x4*)(xrow + 4);
        bf16x8 a;
#pragma unroll
        for (int j = 0; j < 4; ++j) { a[j] = (__bf16)x0[j]; a[4 + j] = (__bf16)x1[j]; }
        *(bf16x8*)&abuf[0][ar][a0] = a;
    }

    for (int kk = 0; kk < 16; ++kk) {
        int buf = kk & 1, nb = buf ^ 1;
        __syncthreads();                      // buf ready (ds_writes + DMA drained)
        f32x4 x0, x1;
        bool hn = (kk + 1) < 16;
        if (hn) {                             // prefetch next step into nb
            const float* xp = xrow + (kk + 1) * BK;
            x0 = *(const f32x4*)(xp);
            x1 = *(const f32x4*)(xp + 4);
#pragma unroll
            for (int i = 0; i < 6; ++i) {
                int p = wave * 6 + i;
                int kh = p / 12, tt = p % 12;
                const __bf16* src = wfrag + (((size_t)(kk + 1) * 2 + kh) * 12 + tt) * 512 + lane * 8;
                __builtin_amdgcn_global_load_lds(
                    (const __attribute__((address_space(1))) void*)src,
                    (__attribute__((address_space(3))) void*)&bbuf[nb][kh][tt][0], 16, 0, 0);
            }
        }
#pragma unroll
        for (int kh = 0; kh < 2; ++kh) {
            bf16x8 af = *(const bf16x8*)&abuf[buf][mh * 16 + c][kh * 32 + g * 8];
#pragma unroll
            for (int t = 0; t < 6; ++t) {
                bf16x8 bfh = *(const bf16x8*)&bbuf[buf][kh][th * 6 + t][lane * 8];
                acc[t] = __builtin_amdgcn_mfma_f32_16x16x32_bf16(af, bfh, acc[t], 0, 0, 0);
            }
        }
        if (hn) {                             // A cvt + write after compute (nb is free)
            bf16x8 a;
#pragma unroll
            for (int j = 0; j < 4; ++j) { a[j] = (__bf16)x0[j]; a[4 + j] = (__bf16)x1[j]; }
            *(bf16x8*)&abuf[nb][ar][a0] = a;
        }
    }

    // epilogue: C layout col = lane&15 (n within t), row = (lane>>4)*4 + r
#pragma unroll
    for (int t = 0; t < 6; ++t) {
        int tg = th * 6 + t;
        int n  = tg * 16 + c;                 // 0..191, wave-uniform section
#pragma unroll
        for (int r = 0; r < 4; ++r) {
            int grow = row0 + mh * 16 + g * 4 + r;
            float v  = acc[t][r];
            // fold 1/sqrt(64) * log2(e) into Q so softmax runs in exp2 domain
            if (n < 64)       Qb[(size_t)grow * HD_ + n] = (__bf16)(v * 0.18033688f);
            else if (n < 128) Kb[(size_t)grow * HD_ + (n - 64)] = (__bf16)v;
            else              Vt[(size_t)(grow >> 11) * (HD_ * T_) + (size_t)(n - 128) * T_ + (grow & 2047)] = (__bf16)v;
        }
    }
}

// ---------------- kernel 2: causal flash attention, kv-split partials --------
// 2048 blocks x 128 threads (2 waves x 16 q-rows; 4 kv-splits per q-tile).
// S^T = K*Q^T (q lane-local), online softmax in exp2 domain, P via per-wave LDS
// relayout, O^T = V^T * P^T. Each split writes partial O + (m, l); comb_k merges.
__global__ __launch_bounds__(128) void attn_k(const __bf16* __restrict__ Qb,
        const __bf16* __restrict__ Kb, const __bf16* __restrict__ Vt,
        float* __restrict__ Opart, float* __restrict__ ml) {
    int split = blockIdx.x >> 9;
    int bid2  = blockIdx.x & 511;
    int half = bid2 >> 8, idx = bid2 & 255;
    int b = idx >> 5, p = idx & 31;
    int qb = half ? (63 - p) : p;            // pair big+small causal extents per CU
    int wave = threadIdx.x >> 6, lane = threadIdx.x & 63;
    int c = lane & 15, g = lane >> 4;
    int qg   = qb * 32 + wave * 16 + c;      // this lane's q row
    int tile = b * 128 + qb * 2 + wave;      // 16-row q-tile id (0..1023)
    int nd2  = (qb + 2) >> 1;                // double-tiles of 64 kv
    float m = -1e30f, lsum = 0.f;
    if (split < nd2) {
        const __bf16* qp = Qb + (size_t)(b * T_ + qg) * HD_ + g * 8;
        bf16x8 qf0 = *(const bf16x8*)qp;
        bf16x8 qf1 = *(const bf16x8*)(qp + 32);
        const __bf16* Kbase = Kb + (size_t)b * T_ * HD_;
        const __bf16* Vbase = Vt + (size_t)b * HD_ * T_;
        f32x4 o0 = (f32x4)0.f, o1 = (f32x4)0.f, o2 = (f32x4)0.f, o3 = (f32x4)0.f;
        __shared__ __bf16 plds[2][16][72];   // per-wave P tile (64 kv), rows padded
        __bf16 (*pl)[72] = plds[wave];
        for (int kt = split; kt < nd2; kt += SPLIT) {
            int kv0 = kt * 64;
            const __bf16* kp = Kbase + (size_t)(kv0 + c) * HD_ + g * 8;
            bf16x8 ka00 = *(const bf16x8*)(kp);
            bf16x8 ka01 = *(const bf16x8*)(kp + 32);
            bf16x8 ka10 = *(const bf16x8*)(kp + 16 * HD_);
            bf16x8 ka11 = *(const bf16x8*)(kp + 16 * HD_ + 32);
            bf16x8 kb00 = *(const bf16x8*)(kp + 32 * HD_);
            bf16x8 kb01 = *(const bf16x8*)(kp + 32 * HD_ + 32);
            bf16x8 kb10 = *(const bf16x8*)(kp + 48 * HD_);
            bf16x8 kb11 = *(const bf16x8*)(kp + 48 * HD_ + 32);
            f32x4 sa0 = (f32x4)0.f, sa1 = (f32x4)0.f, sb0 = (f32x4)0.f, sb1 = (f32x4)0.f;
            sa0 = __builtin_amdgcn_mfma_f32_16x16x32_bf16(ka00, qf0, sa0, 0, 0, 0);
            sa0 = __builtin_amdgcn_mfma_f32_16x16x32_bf16(ka01, qf1, sa0, 0, 0, 0);
            sa1 = __builtin_amdgcn_mfma_f32_16x16x32_bf16(ka10, qf0, sa1, 0, 0, 0);
            sa1 = __builtin_amdgcn_mfma_f32_16x16x32_bf16(ka11, qf1, sa1, 0, 0, 0);
            sb0 = __builtin_amdgcn_mfma_f32_16x16x32_bf16(kb00, qf0, sb0, 0, 0, 0);
            sb0 = __builtin_amdgcn_mfma_f32_16x16x32_bf16(kb01, qf1, sb0, 0, 0, 0);
            sb1 = __builtin_amdgcn_mfma_f32_16x16x32_bf16(kb10, qf0, sb1, 0, 0, 0);
            sb1 = __builtin_amdgcn_mfma_f32_16x16x32_bf16(kb11, qf1, sb1, 0, 0, 0);
            float s[16];
#pragma unroll
            for (int r = 0; r < 4; ++r) {
                s[r] = sa0[r]; s[4 + r] = sa1[r]; s[8 + r] = sb0[r]; s[12 + r] = sb1[r];
            }
            if (kt == nd2 - 1) {             // only the final double-tile needs masking
#pragma unroll
                for (int i = 0; i < 16; ++i) {
                    int kv = kv0 + (i >> 2) * 16 + g * 4 + (i & 3);
                    if (kv > qg) s[i] = -1e30f;
                }
            }
            float tm = s[0];
#pragma unroll
            for (int i = 1; i < 16; ++i) tm = fmaxf(tm, s[i]);
            tm = fmaxf(tm, __shfl_xor(tm, 16));
            tm = fmaxf(tm, __shfl_xor(tm, 32));
            float mn = fmaxf(m, tm);
            float al = __builtin_amdgcn_exp2f(m - mn);
            float ps = 0.f;
#pragma unroll
            for (int i = 0; i < 16; ++i) { s[i] = __builtin_amdgcn_exp2f(s[i] - mn); ps += s[i]; }
            ps += __shfl_xor(ps, 16);
            ps += __shfl_xor(ps, 32);
            lsum = lsum * al + ps;
            m = mn;
            o0 *= al; o1 *= al; o2 *= al; o3 *= al;
            // P (this lane: q=c, kv = (i>>2)*16 + g*4 + (i&3)) -> LDS as P[q][kv]
#pragma unroll
            for (int mt = 0; mt < 4; ++mt) {
                bf16x4 pv;
#pragma unroll
                for (int r = 0; r < 4; ++r) pv[r] = (__bf16)s[mt * 4 + r];
                *(bf16x4*)&pl[c][mt * 16 + g * 4] = pv;
            }
            // B-frag reads: P[q=c][kv = tile*32 + g*8 + j], wave-private (no barrier)
            bf16x8 pf0 = *(const bf16x8*)&pl[c][g * 8];
            bf16x8 pf1 = *(const bf16x8*)&pl[c][32 + g * 8];
            const __bf16* vp = Vbase + (size_t)c * T_ + kv0 + g * 8;
            bf16x8 v0a = *(const bf16x8*)(vp);
            bf16x8 v1a = *(const bf16x8*)(vp + 16 * T_);
            bf16x8 v2a = *(const bf16x8*)(vp + 32 * T_);
            bf16x8 v3a = *(const bf16x8*)(vp + 48 * T_);
            bf16x8 v0b = *(const bf16x8*)(vp + 32);
            bf16x8 v1b = *(const bf16x8*)(vp + 16 * T_ + 32);
            bf16x8 v2b = *(const bf16x8*)(vp + 32 * T_ + 32);
            bf16x8 v3b = *(const bf16x8*)(vp + 48 * T_ + 32);
            o0 = __builtin_amdgcn_mfma_f32_16x16x32_bf16(v0a, pf0, o0, 0, 0, 0);
            o1 = __builtin_amdgcn_mfma_f32_16x16x32_bf16(v1a, pf0, o1, 0, 0, 0);
            o2 = __builtin_amdgcn_mfma_f32_16x16x32_bf16(v2a, pf0, o2, 0, 0, 0);
            o3 = __builtin_amdgcn_mfma_f32_16x16x32_bf16(v3a, pf0, o3, 0, 0, 0);
            o0 = __builtin_amdgcn_mfma_f32_16x16x32_bf16(v0b, pf1, o0, 0, 0, 0);
            o1 = __builtin_amdgcn_mfma_f32_16x16x32_bf16(v1b, pf1, o1, 0, 0, 0);
            o2 = __builtin_amdgcn_mfma_f32_16x16x32_bf16(v2b, pf1, o2, 0, 0, 0);
            o3 = __builtin_amdgcn_mfma_f32_16x16x32_bf16(v3b, pf1, o3, 0, 0, 0);
        }
        // partial O^T store: Opart[part][q_local=c][d = dt*16 + g*4 + r]
        float* op = Opart + ((size_t)tile * SPLIT + split) * 1024 + c * 64 + g * 4;
        *(f32x4*)(op)      = o0;
        *(f32x4*)(op + 16) = o1;
        *(f32x4*)(op + 32) = o2;
        *(f32x4*)(op + 48) = o3;
    }
    if (g == 0) {                            // (m, l) per q row; l==0 marks empty split
        float* mlp = ml + ((size_t)tile * SPLIT + split) * 32 + c * 2;
        mlp[0] = m; mlp[1] = lsum;
    }
}

// ---------------- kernel 3: merge kv-split partials, normalize, mask ---------
// 1024 blocks x 256 threads; block = one 16-row q-tile; thread = (q, 4 d's).
__global__ __launch_bounds__(256) void comb_k(const float* __restrict__ Opart,
        const float* __restrict__ ml, const int* __restrict__ vlen,
        float* __restrict__ out) {
    int tile = blockIdx.x;
    int b  = tile >> 7;
    int q0 = (tile & 127) * 16;
    int q  = threadIdx.x >> 4;
    int d0 = (threadIdx.x & 15) * 4;
    int qg = q0 + q;
    const float* mlp = ml + (size_t)tile * SPLIT * 32 + q * 2;
    float mj[SPLIT], lj[SPLIT];
#pragma unroll
    for (int j = 0; j < SPLIT; ++j) { mj[j] = mlp[j * 32]; lj[j] = mlp[j * 32 + 1]; }
    float M = fmaxf(fmaxf(mj[0], mj[1]), fmaxf(mj[2], mj[3]));
    f32x4 acc = (f32x4)0.f;
    float L = 0.f;
#pragma unroll
    for (int j = 0; j < SPLIT; ++j) {
        if (lj[j] > 0.f) {                   // skip empty splits (Opart unwritten there)
            float sc = __builtin_amdgcn_exp2f(mj[j] - M);
            L += lj[j] * sc;
            f32x4 ov = *(const f32x4*)(Opart + ((size_t)tile * SPLIT + j) * 1024 + q * 64 + d0);
            acc += ov * sc;
        }
    }
    float inv = (qg < vlen[b]) ? 1.f / L : 0.f;  // dead rows -> 0
    f32x4 r = acc * inv;
    *(f32x4*)(out + ((size_t)(b * T_) + qg) * HD_ + d0) = r;
}

extern "C" void kernel_launch(void* const* d_in, const int* in_sizes, int n_in,
                              void* d_out, int out_size, void* d_ws, size_t ws_size,
                              hipStream_t stream) {
    const float* x   = (const float*)d_in[0];
    const float* Wq  = (const float*)d_in[1];
    const float* Wk  = (const float*)d_in[2];
    const float* Wv  = (const float*)d_in[3];
    const int*   vln = (const int*)d_in[4];
    float* out = (float*)d_out;

    __bf16* Qb    = (__bf16*)d_ws;                 // 16384*64 bf16 = 2MB
    __bf16* Kb    = Qb + (size_t)NROW * HD_;       // 2MB
    __bf16* Vt    = Kb + (size_t)NROW * HD_;       // 2MB (V transposed per batch: [b][d][t])
    __bf16* wfrag = Vt + (size_t)NROW * HD_;       // 384KB frag-ordered weights
    float*  Opart = (float*)(wfrag + 24576 * 8);   // 1024 tiles x 4 splits x 16x64 f32 = 16MB
    float*  mlbuf = Opart + (size_t)1024 * SPLIT * 1024;  // 512KB (m,l) pairs

    wconv_k<<<96, 256, 0, stream>>>(Wq, Wk, Wv, wfrag);
    proj_k <<<512, 256, 0, stream>>>(x, wfrag, Qb, Kb, Vt);
    attn_k <<<512 * SPLIT, 128, 0, stream>>>(Qb, Kb, Vt, Opart, mlbuf);
    comb_k <<<1024, 256, 0, stream>>>(Opart, mlbuf, vln, out);
}

// Round 5
// 151.991 us; speedup vs baseline: 1.1665x; 1.0232x over previous
//
#include <hip/hip_runtime.h>
#include <hip/hip_bf16.h>
#include <stdint.h>

#define T_   2048
#define DM_  1024
#define HD_  64
#define NROW 16384  // B*T
#define SPLIT 4     // kv-splits per q-tile (occupancy lever for attn)
#define BM   32     // proj rows per block
#define BK   64     // proj k per step

typedef __attribute__((ext_vector_type(8))) __bf16 bf16x8;
typedef __attribute__((ext_vector_type(4))) __bf16 bf16x4;
typedef __attribute__((ext_vector_type(4))) float  f32x4;

// ---------------- kernel 0: pack [Wq|Wk|Wv] -> bf16 B-fragment order ----------
// frag layout: index ((kc*12 + t)*64 + lane)*8 + j  holds W[k = kc*32 + (lane>>4)*8 + j][n = t*16 + (lane&15)]
__global__ void wconv_k(const float* __restrict__ Wq, const float* __restrict__ Wk,
                        const float* __restrict__ Wv, __bf16* __restrict__ wfrag) {
    int tid  = blockIdx.x * 256 + threadIdx.x;   // 24576 total
    int lane = tid & 63;
    int t    = (tid >> 6) % 12;
    int kc   = tid / (12 * 64);
    int c = lane & 15, g = lane >> 4;
    int n = t * 16 + c;
    const float* W = (n < 64) ? Wq : (n < 128) ? Wk : Wv;
    int col = n & 63;
    int k0  = kc * 32 + g * 8;
    __bf16* dst = wfrag + (size_t)tid * 8;
#pragma unroll
    for (int j = 0; j < 8; ++j) dst[j] = (__bf16)W[(k0 + j) * HD_ + col];
}

// ---------------- kernel 1: QKV projection GEMM (16384x192x1024, bf16 MFMA) ---
// LDS-staged double-buffered: coalesced x->LDS (padded), wfrag->LDS via
// global_load_lds (per-block, not per-wave). 512 blocks x 256 thr, 2 blocks/CU.
__global__ __launch_bounds__(256, 2) void proj_k(const float* __restrict__ x,
        const __bf16* __restrict__ wfrag, __bf16* __restrict__ Qb,
        __bf16* __restrict__ Kb, __bf16* __restrict__ Vt) {
    __shared__ __bf16 abuf[2][BM][72];        // A tile bf16, row-padded (+8) -> 2-way only
    __shared__ __bf16 bbuf[2][2][12][512];    // [buf][khalf][t][lane*8] linear frag order
    int tid  = threadIdx.x;
    int lane = tid & 63, wave = tid >> 6;
    int mh = wave >> 1, th = wave & 1;        // wave = 16-row half x 6-t half
    int c = lane & 15, g = lane >> 4;
    int row0 = blockIdx.x * BM;
    int ar = tid >> 3, a0 = (tid & 7) * 8;    // staging: thread = (row, 8-col chunk)
    const float* xrow = x + (size_t)(row0 + ar) * DM_ + a0;

    f32x4 acc[6];
#pragma unroll
    for (int t = 0; t < 6; ++t) acc[t] = (f32x4)0.f;

    // prologue: stage step 0 into buf 0
    {
#pragma unroll
        for (int i = 0; i < 6; ++i) {
            int p = wave * 6 + i;             // 24 (khalf,t) frags split across 4 waves
            int kh = p / 12, tt = p % 12;
            const __bf16* src = wfrag + ((size_t)kh * 12 + tt) * 512 + lane * 8;
            __builtin_amdgcn_global_load_lds(
                (const __attribute__((address_space(1))) void*)src,
                (__attribute__((address_space(3))) void*)&bbuf[0][kh][tt][0], 16, 0, 0);
        }
        f32x4 x0 = *(const f32x4*)(xrow);
        f32x4 x1 = *(const f32x4*)(xrow + 4);
        bf16x8 a;
#pragma unroll
        for (int j = 0; j < 4; ++j) { a[j] = (__bf16)x0[j]; a[4 + j] = (__bf16)x1[j]; }
        *(bf16x8*)&abuf[0][ar][a0] = a;
    }

    for (int kk = 0; kk < 16; ++kk) {
        int buf = kk & 1, nb = buf ^ 1;
        __syncthreads();                      // buf ready (ds_writes + DMA drained)
        f32x4 x0, x1;
        bool hn = (kk + 1) < 16;
        if (hn) {                             // prefetch next step into nb
            const float* xp = xrow + (kk + 1) * BK;
            x0 = *(const f32x4*)(xp);
            x1 = *(const f32x4*)(xp + 4);
#pragma unroll
            for (int i = 0; i < 6; ++i) {
                int p = wave * 6 + i;
                int kh = p / 12, tt = p % 12;
                const __bf16* src = wfrag + (((size_t)(kk + 1) * 2 + kh) * 12 + tt) * 512 + lane * 8;
                __builtin_amdgcn_global_load_lds(
                    (const __attribute__((address_space(1))) void*)src,
                    (__attribute__((address_space(3))) void*)&bbuf[nb][kh][tt][0], 16, 0, 0);
            }
        }
#pragma unroll
        for (int kh = 0; kh < 2; ++kh) {
            bf16x8 af = *(const bf16x8*)&abuf[buf][mh * 16 + c][kh * 32 + g * 8];
#pragma unroll
            for (int t = 0; t < 6; ++t) {
                bf16x8 bfh = *(const bf16x8*)&bbuf[buf][kh][th * 6 + t][lane * 8];
                acc[t] = __builtin_amdgcn_mfma_f32_16x16x32_bf16(af, bfh, acc[t], 0, 0, 0);
            }
        }
        if (hn) {                             // A cvt + write after compute (nb is free)
            bf16x8 a;
#pragma unroll
            for (int j = 0; j < 4; ++j) { a[j] = (__bf16)x0[j]; a[4 + j] = (__bf16)x1[j]; }
            *(bf16x8*)&abuf[nb][ar][a0] = a;
        }
    }

    // epilogue: C layout col = lane&15 (n within t), row = (lane>>4)*4 + r
#pragma unroll
    for (int t = 0; t < 6; ++t) {
        int tg = th * 6 + t;
        int n  = tg * 16 + c;                 // 0..191, wave-uniform section
#pragma unroll
        for (int r = 0; r < 4; ++r) {
            int grow = row0 + mh * 16 + g * 4 + r;
            float v  = acc[t][r];
            // fold 1/sqrt(64) * log2(e) into Q so softmax runs in exp2 domain
            if (n < 64)       Qb[(size_t)grow * HD_ + n] = (__bf16)(v * 0.18033688f);
            else if (n < 128) Kb[(size_t)grow * HD_ + (n - 64)] = (__bf16)v;
            else              Vt[(size_t)(grow >> 11) * (HD_ * T_) + (size_t)(n - 128) * T_ + (grow & 2047)] = (__bf16)v;
        }
    }
}

// ---------------- kernel 2: causal flash attention, kv-split partials --------
// 2048 blocks x 128 threads (2 waves x 16 q-rows; 4 kv-splits per q-tile).
// S^T = K*Q^T (q lane-local), online softmax in exp2 domain, P via per-wave LDS
// relayout, O^T = V^T * P^T. All 16 loads (K+V) issued at iteration top so V
// flies under QK+softmax; launch_bounds(128,2) caps at 256 VGPR so they stay
// in flight (68-VGPR squeeze was serializing them).
__global__ __launch_bounds__(128, 2) void attn_k(const __bf16* __restrict__ Qb,
        const __bf16* __restrict__ Kb, const __bf16* __restrict__ Vt,
        float* __restrict__ Opart, float* __restrict__ ml) {
    int split = blockIdx.x >> 9;
    int bid2  = blockIdx.x & 511;
    int half = bid2 >> 8, idx = bid2 & 255;
    int b = idx >> 5, p = idx & 31;
    int qb = half ? (63 - p) : p;            // pair big+small causal extents per CU
    int wave = threadIdx.x >> 6, lane = threadIdx.x & 63;
    int c = lane & 15, g = lane >> 4;
    int qg   = qb * 32 + wave * 16 + c;      // this lane's q row
    int tile = b * 128 + qb * 2 + wave;      // 16-row q-tile id (0..1023)
    int nd2  = (qb + 2) >> 1;                // double-tiles of 64 kv
    float m = -1e30f, lsum = 0.f;
    if (split < nd2) {
        const __bf16* qp = Qb + (size_t)(b * T_ + qg) * HD_ + g * 8;
        bf16x8 qf0 = *(const bf16x8*)qp;
        bf16x8 qf1 = *(const bf16x8*)(qp + 32);
        const __bf16* Kbase = Kb + (size_t)b * T_ * HD_;
        const __bf16* Vbase = Vt + (size_t)b * HD_ * T_;
        f32x4 o0 = (f32x4)0.f, o1 = (f32x4)0.f, o2 = (f32x4)0.f, o3 = (f32x4)0.f;
        __shared__ __bf16 plds[2][16][72];   // per-wave P tile (64 kv), rows padded
        __bf16 (*pl)[72] = plds[wave];
        for (int kt = split; kt < nd2; kt += SPLIT) {
            int kv0 = kt * 64;
            // ---- issue ALL loads up front: K (needed by QK) then V (needed late)
            const __bf16* kp = Kbase + (size_t)(kv0 + c) * HD_ + g * 8;
            bf16x8 ka00 = *(const bf16x8*)(kp);
            bf16x8 ka01 = *(const bf16x8*)(kp + 32);
            bf16x8 ka10 = *(const bf16x8*)(kp + 16 * HD_);
            bf16x8 ka11 = *(const bf16x8*)(kp + 16 * HD_ + 32);
            bf16x8 kb00 = *(const bf16x8*)(kp + 32 * HD_);
            bf16x8 kb01 = *(const bf16x8*)(kp + 32 * HD_ + 32);
            bf16x8 kb10 = *(const bf16x8*)(kp + 48 * HD_);
            bf16x8 kb11 = *(const bf16x8*)(kp + 48 * HD_ + 32);
            const __bf16* vp = Vbase + (size_t)c * T_ + kv0 + g * 8;
            bf16x8 v0a = *(const bf16x8*)(vp);
            bf16x8 v1a = *(const bf16x8*)(vp + 16 * T_);
            bf16x8 v2a = *(const bf16x8*)(vp + 32 * T_);
            bf16x8 v3a = *(const bf16x8*)(vp + 48 * T_);
            bf16x8 v0b = *(const bf16x8*)(vp + 32);
            bf16x8 v1b = *(const bf16x8*)(vp + 16 * T_ + 32);
            bf16x8 v2b = *(const bf16x8*)(vp + 32 * T_ + 32);
            bf16x8 v3b = *(const bf16x8*)(vp + 48 * T_ + 32);
            f32x4 sa0 = (f32x4)0.f, sa1 = (f32x4)0.f, sb0 = (f32x4)0.f, sb1 = (f32x4)0.f;
            sa0 = __builtin_amdgcn_mfma_f32_16x16x32_bf16(ka00, qf0, sa0, 0, 0, 0);
            sa0 = __builtin_amdgcn_mfma_f32_16x16x32_bf16(ka01, qf1, sa0, 0, 0, 0);
            sa1 = __builtin_amdgcn_mfma_f32_16x16x32_bf16(ka10, qf0, sa1, 0, 0, 0);
            sa1 = __builtin_amdgcn_mfma_f32_16x16x32_bf16(ka11, qf1, sa1, 0, 0, 0);
            sb0 = __builtin_amdgcn_mfma_f32_16x16x32_bf16(kb00, qf0, sb0, 0, 0, 0);
            sb0 = __builtin_amdgcn_mfma_f32_16x16x32_bf16(kb01, qf1, sb0, 0, 0, 0);
            sb1 = __builtin_amdgcn_mfma_f32_16x16x32_bf16(kb10, qf0, sb1, 0, 0, 0);
            sb1 = __builtin_amdgcn_mfma_f32_16x16x32_bf16(kb11, qf1, sb1, 0, 0, 0);
            float s[16];
#pragma unroll
            for (int r = 0; r < 4; ++r) {
                s[r] = sa0[r]; s[4 + r] = sa1[r]; s[8 + r] = sb0[r]; s[12 + r] = sb1[r];
            }
            if (kt == nd2 - 1) {             // only the final double-tile needs masking
#pragma unroll
                for (int i = 0; i < 16; ++i) {
                    int kv = kv0 + (i >> 2) * 16 + g * 4 + (i & 3);
                    if (kv > qg) s[i] = -1e30f;
                }
            }
            // tree max (depth 4, not serial 15-chain)
            float m0 = fmaxf(fmaxf(s[0], s[1]), fmaxf(s[2], s[3]));
            float m1 = fmaxf(fmaxf(s[4], s[5]), fmaxf(s[6], s[7]));
            float m2 = fmaxf(fmaxf(s[8], s[9]), fmaxf(s[10], s[11]));
            float m3 = fmaxf(fmaxf(s[12], s[13]), fmaxf(s[14], s[15]));
            float tm = fmaxf(fmaxf(m0, m1), fmaxf(m2, m3));
            tm = fmaxf(tm, __shfl_xor(tm, 16));
            tm = fmaxf(tm, __shfl_xor(tm, 32));
            float mn = fmaxf(m, tm);
            float al = __builtin_amdgcn_exp2f(m - mn);
#pragma unroll
            for (int i = 0; i < 16; ++i) s[i] = __builtin_amdgcn_exp2f(s[i] - mn);
            // tree sum
            float p0 = (s[0] + s[1]) + (s[2] + s[3]);
            float p1 = (s[4] + s[5]) + (s[6] + s[7]);
            float p2 = (s[8] + s[9]) + (s[10] + s[11]);
            float p3 = (s[12] + s[13]) + (s[14] + s[15]);
            float ps = (p0 + p1) + (p2 + p3);
            ps += __shfl_xor(ps, 16);
            ps += __shfl_xor(ps, 32);
            lsum = lsum * al + ps;
            m = mn;
            o0 *= al; o1 *= al; o2 *= al; o3 *= al;
            // P (this lane: q=c, kv = (i>>2)*16 + g*4 + (i&3)) -> LDS as P[q][kv]
#pragma unroll
            for (int mt = 0; mt < 4; ++mt) {
                bf16x4 pv;
#pragma unroll
                for (int r = 0; r < 4; ++r) pv[r] = (__bf16)s[mt * 4 + r];
                *(bf16x4*)&pl[c][mt * 16 + g * 4] = pv;
            }
            // B-frag reads: P[q=c][kv = tile*32 + g*8 + j], wave-private (no barrier)
            bf16x8 pf0 = *(const bf16x8*)&pl[c][g * 8];
            bf16x8 pf1 = *(const bf16x8*)&pl[c][32 + g * 8];
            o0 = __builtin_amdgcn_mfma_f32_16x16x32_bf16(v0a, pf0, o0, 0, 0, 0);
            o1 = __builtin_amdgcn_mfma_f32_16x16x32_bf16(v1a, pf0, o1, 0, 0, 0);
            o2 = __builtin_amdgcn_mfma_f32_16x16x32_bf16(v2a, pf0, o2, 0, 0, 0);
            o3 = __builtin_amdgcn_mfma_f32_16x16x32_bf16(v3a, pf0, o3, 0, 0, 0);
            o0 = __builtin_amdgcn_mfma_f32_16x16x32_bf16(v0b, pf1, o0, 0, 0, 0);
            o1 = __builtin_amdgcn_mfma_f32_16x16x32_bf16(v1b, pf1, o1, 0, 0, 0);
            o2 = __builtin_amdgcn_mfma_f32_16x16x32_bf16(v2b, pf1, o2, 0, 0, 0);
            o3 = __builtin_amdgcn_mfma_f32_16x16x32_bf16(v3b, pf1, o3, 0, 0, 0);
        }
        // partial O^T store: Opart[part][q_local=c][d = dt*16 + g*4 + r]
        float* op = Opart + ((size_t)tile * SPLIT + split) * 1024 + c * 64 + g * 4;
        *(f32x4*)(op)      = o0;
        *(f32x4*)(op + 16) = o1;
        *(f32x4*)(op + 32) = o2;
        *(f32x4*)(op + 48) = o3;
    }
    if (g == 0) {                            // (m, l) per q row; l==0 marks empty split
        float* mlp = ml + ((size_t)tile * SPLIT + split) * 32 + c * 2;
        mlp[0] = m; mlp[1] = lsum;
    }
}

// ---------------- kernel 3: merge kv-split partials, normalize, mask ---------
// 1024 blocks x 256 threads; block = one 16-row q-tile; thread = (q, 4 d's).
__global__ __launch_bounds__(256) void comb_k(const float* __restrict__ Opart,
        const float* __restrict__ ml, const int* __restrict__ vlen,
        float* __restrict__ out) {
    int tile = blockIdx.x;
    int b  = tile >> 7;
    int q0 = (tile & 127) * 16;
    int q  = threadIdx.x >> 4;
    int d0 = (threadIdx.x & 15) * 4;
    int qg = q0 + q;
    const float* mlp = ml + (size_t)tile * SPLIT * 32 + q * 2;
    float mj[SPLIT], lj[SPLIT];
#pragma unroll
    for (int j = 0; j < SPLIT; ++j) { mj[j] = mlp[j * 32]; lj[j] = mlp[j * 32 + 1]; }
    float M = fmaxf(fmaxf(mj[0], mj[1]), fmaxf(mj[2], mj[3]));
    f32x4 acc = (f32x4)0.f;
    float L = 0.f;
#pragma unroll
    for (int j = 0; j < SPLIT; ++j) {
        if (lj[j] > 0.f) {                   // skip empty splits (Opart unwritten there)
            float sc = __builtin_amdgcn_exp2f(mj[j] - M);
            L += lj[j] * sc;
            f32x4 ov = *(const f32x4*)(Opart + ((size_t)tile * SPLIT + j) * 1024 + q * 64 + d0);
            acc += ov * sc;
        }
    }
    float inv = (qg < vlen[b]) ? 1.f / L : 0.f;  // dead rows -> 0
    f32x4 r = acc * inv;
    *(f32x4*)(out + ((size_t)(b * T_) + qg) * HD_ + d0) = r;
}

extern "C" void kernel_launch(void* const* d_in, const int* in_sizes, int n_in,
                              void* d_out, int out_size, void* d_ws, size_t ws_size,
                              hipStream_t stream) {
    const float* x   = (const float*)d_in[0];
    const float* Wq  = (const float*)d_in[1];
    const float* Wk  = (const float*)d_in[2];
    const float* Wv  = (const float*)d_in[3];
    const int*   vln = (const int*)d_in[4];
    float* out = (float*)d_out;

    __bf16* Qb    = (__bf16*)d_ws;                 // 16384*64 bf16 = 2MB
    __bf16* Kb    = Qb + (size_t)NROW * HD_;       // 2MB
    __bf16* Vt    = Kb + (size_t)NROW * HD_;       // 2MB (V transposed per batch: [b][d][t])
    __bf16* wfrag = Vt + (size_t)NROW * HD_;       // 384KB frag-ordered weights
    float*  Opart = (float*)(wfrag + 24576 * 8);   // 1024 tiles x 4 splits x 16x64 f32 = 16MB
    float*  mlbuf = Opart + (size_t)1024 * SPLIT * 1024;  // 512KB (m,l) pairs

    wconv_k<<<96, 256, 0, stream>>>(Wq, Wk, Wv, wfrag);
    proj_k <<<512, 256, 0, stream>>>(x, wfrag, Qb, Kb, Vt);
    attn_k <<<512 * SPLIT, 128, 0, stream>>>(Qb, Kb, Vt, Opart, mlbuf);
    comb_k <<<1024, 256, 0, stream>>>(Opart, mlbuf, vln, out);
}